// Round 9
// baseline (746.487 us; speedup 1.0000x reference)
//
#include <hip/hip_runtime.h>
#include <hip/hip_bf16.h>
#include <stdint.h>

typedef __attribute__((ext_vector_type(8))) short short8;
typedef __attribute__((ext_vector_type(4))) float floatx4;

#define AS1 __attribute__((address_space(1)))
#define AS3 __attribute__((address_space(3)))

__device__ __forceinline__ void async_copy16(const void* g, void* l) {
    __builtin_amdgcn_global_load_lds((const AS1 uint32_t*)(uintptr_t)g,
                                     (AS3 uint32_t*)(uintptr_t)l, 16, 0, 0);
}

// load 8 f32 -> 8 bf16 packed
__device__ __forceinline__ short8 cvt8(const float* p) {
    float4 a = *(const float4*)p;
    float4 b = *(const float4*)(p + 4);
    union { short s[8]; short8 v; } u;
    __hip_bfloat16* h = (__hip_bfloat16*)u.s;
    h[0] = __float2bfloat16(a.x); h[1] = __float2bfloat16(a.y);
    h[2] = __float2bfloat16(a.z); h[3] = __float2bfloat16(a.w);
    h[4] = __float2bfloat16(b.x); h[5] = __float2bfloat16(b.y);
    h[6] = __float2bfloat16(b.z); h[7] = __float2bfloat16(b.w);
    return u.v;
}

// ---------------------------------------------------------------- cvt f32->bf16
__global__ __launch_bounds__(256) void cvt_bf16(const float* __restrict__ s,
                                                __hip_bfloat16* __restrict__ d, int n) {
    int i = ((int)blockIdx.x * 256 + (int)threadIdx.x) * 4;
    if (i >= n) return;
    const float4 v = *(const float4*)(s + i);
    ushort4 pk;
    __hip_bfloat16* ph = (__hip_bfloat16*)&pk;
    ph[0] = __float2bfloat16(v.x); ph[1] = __float2bfloat16(v.y);
    ph[2] = __float2bfloat16(v.z); ph[3] = __float2bfloat16(v.w);
    *(ushort4*)(d + i) = pk;
}

// ---------------------------------------------------------------- V transpose
// Vn [t][2048] -> Vt[(b*16+nh)*128+d][s]. Writes coalesced 16B/lane; scattered
// side is the READ side (L2 absorbs) -- r5 lesson.
__global__ __launch_bounds__(256) void vtrans(const __hip_bfloat16* __restrict__ Vn,
                                              __hip_bfloat16* __restrict__ Vt) {
    int idx = (int)blockIdx.x * 256 + (int)threadIdx.x;
    int sc  = idx & 255;
    int d   = (idx >> 8) & 127;
    int bh  = idx >> 15;
    int b   = bh >> 4, nh = bh & 15;
    union { short h[8]; short8 v; } u;
#pragma unroll
    for (int j = 0; j < 8; ++j) {
        int t = (sc * 8 + j) * 4 + b;
        u.h[j] = *(const short*)(Vn + (size_t)t * 2048 + nh * 128 + d);
    }
    *(short8*)(Vt + ((size_t)bh * 128 + d) * 2048 + sc * 8) = u.v;
}

// ---------------------------------------------------------------- GEMM 256x256
// C = A(bf16) @ B(f32,row-major-K)^T + bias. M=8192 N=2048 K=2048, 8 waves 2Mx4N.
// A staged via global_load_lds (4/tile); B staged f32->reg->cvt->ds_write
// (8 dwordx4/tile + 4 ds_write_b128) -- removes the separate weight-cvt kernels
// (their 96 MB/weight of convert traffic) at +8 MB f32 read per gemm.
// vmcnt ledger: at tile top, outstanding = A(kt) 4 (B(kt) regs were consumed by
// writeB last tile, compiler-waited); issue B(kt+1) 8 + A(kt+1) 4 -> vmcnt(12)
// retires exactly A(kt). writeB's breg use is compiler-guarded (correct for any
// issue order). lgkmcnt(0) before the tile-top barrier publishes ds_writes.
template <int STORE_MODE, int SCALE_OUT>
__global__ __launch_bounds__(512, 2) void gemm256(const __hip_bfloat16* __restrict__ Ab,
                                                  const float* __restrict__ Bf,
                                                  const float* __restrict__ bias,
                                                  void* __restrict__ Cv) {
    constexpr int N = 2048, K = 2048;
    __shared__ __align__(16) char smem[131072];
    char* smemA = smem;            // +((cur*2)+kh)*16384
    char* smemB = smem + 65536;
    const int tid  = threadIdx.x;
    const int wave = tid >> 6, lane = tid & 63;
    const int quad = lane >> 4, l16 = lane & 15;
    const int wm = wave >> 2, wn = wave & 3;
    // XCD-contiguous swizzle (256 blocks, 8 XCDs -> contiguous 4Mx8N panels)
    const int wg = ((int)blockIdx.x & 7) * 32 + ((int)blockIdx.x >> 3);
    const int m0 = (wg >> 3) * 256;
    const int n0 = (wg & 7) * 256;
    // fragment read offset in a [256][64B] arena (128B macro-rows, chunk swz
    // cc^=mm&7); verified conflict-free (r5: SQ_LDS_BANK_CONFLICT = 0)
    const int laneOff = (l16 >> 1) * 128 + (((((l16 & 1) << 2) | quad)) ^ (l16 >> 1)) * 16;

    // staging geometry shared by A-async and B-reg paths
    const int mm_ = wave * 8 + (lane >> 3);  // + i*64 -> macro-row
    const int cc_ = (lane & 7) ^ (lane >> 3);
    const int rr_ = cc_ >> 2;                // row = 2*(i*64+mm_) + rr_
    const int c8_ = (cc_ & 3) * 8;           // elem col offset in 32-col half

    auto stageA = [&](int buf, int col0) {
#pragma unroll
        for (int kh = 0; kh < 2; ++kh) {
            char* arena = smemA + (buf * 2 + kh) * 16384;
#pragma unroll
            for (int i = 0; i < 2; ++i) {
                int s = i * 512 + wave * 64 + lane;
                int r = 2 * (i * 64 + mm_) + rr_;
                async_copy16(Ab + (size_t)(m0 + r) * K + col0 + kh * 32 + c8_,
                             arena + s * 16);
            }
        }
    };

    float4 breg[2][2][2];  // [kh][i][lo/hi 4 floats]
    auto loadB = [&](int col0) {
#pragma unroll
        for (int kh = 0; kh < 2; ++kh)
#pragma unroll
            for (int i = 0; i < 2; ++i) {
                int r = 2 * (i * 64 + mm_) + rr_;
                const float* src = Bf + (size_t)(n0 + r) * K + col0 + kh * 32 + c8_;
                breg[kh][i][0] = *(const float4*)src;
                breg[kh][i][1] = *(const float4*)(src + 4);
            }
    };
    auto writeB = [&](int buf) {
#pragma unroll
        for (int kh = 0; kh < 2; ++kh) {
            char* arena = smemB + (buf * 2 + kh) * 16384;
#pragma unroll
            for (int i = 0; i < 2; ++i) {
                int s = i * 512 + wave * 64 + lane;
                union { short sh[8]; short8 v; } u;
                __hip_bfloat16* h = (__hip_bfloat16*)u.sh;
                float4 a = breg[kh][i][0], b = breg[kh][i][1];
                h[0] = __float2bfloat16(a.x); h[1] = __float2bfloat16(a.y);
                h[2] = __float2bfloat16(a.z); h[3] = __float2bfloat16(a.w);
                h[4] = __float2bfloat16(b.x); h[5] = __float2bfloat16(b.y);
                h[6] = __float2bfloat16(b.z); h[7] = __float2bfloat16(b.w);
                *(short8*)(arena + s * 16) = u.v;
            }
        }
    };

    floatx4 acc[8][4];
#pragma unroll
    for (int i = 0; i < 8; ++i)
#pragma unroll
        for (int j = 0; j < 4; ++j) acc[i][j] = (floatx4)0.0f;

    const int nt = K / 64;  // 32 K-tiles

    // prologue: tile 0 fully staged into buf0
    loadB(0);
    stageA(0, 0);
    writeB(0);  // compiler inserts vmcnt for breg use

    for (int kt = 0; kt < nt; ++kt) {
        const int  cur = kt & 1;
        const bool st  = (kt + 1) < nt;
        asm volatile("s_waitcnt lgkmcnt(0)" ::: "memory");  // publish ds_writes
        __builtin_amdgcn_s_barrier();        // buf[cur] ready for all waves
        __builtin_amdgcn_sched_barrier(0);
        if (st) {
            const int colb = (kt + 1) * 64;
            loadB(colb);             // 8 f32 loads -> regs (tile kt+1)
            stageA(cur ^ 1, colb);   // 4 asyncs -> buf[cur^1]
            asm volatile("s_waitcnt vmcnt(12)" ::: "memory");  // A(kt) landed
        } else {
            asm volatile("s_waitcnt vmcnt(0)" ::: "memory");
        }
        __builtin_amdgcn_sched_barrier(0);

#pragma unroll
        for (int kh = 0; kh < 2; ++kh) {
            const char* Ab_ = smemA + (cur * 2 + kh) * 16384 + wm * 8192;
            const char* Bb_ = smemB + (cur * 2 + kh) * 16384 + wn * 4096;
            short8 bfr[4], afr[8];
#pragma unroll
            for (int n = 0; n < 4; ++n)
                bfr[n] = *(const short8*)(Bb_ + n * 1024 + laneOff);
#pragma unroll
            for (int i = 0; i < 8; ++i)
                afr[i] = *(const short8*)(Ab_ + i * 1024 + laneOff);
            __builtin_amdgcn_s_setprio(1);
#pragma unroll
            for (int i = 0; i < 8; ++i)
#pragma unroll
                for (int n = 0; n < 4; ++n)
                    acc[i][n] = __builtin_amdgcn_mfma_f32_16x16x32_bf16(
                        afr[i], bfr[n], acc[i][n], 0, 0, 0);
            __builtin_amdgcn_s_setprio(0);
        }
        if (st) writeB(cur ^ 1);  // cvt + 4 ds_write; breg waits compiler-inserted
    }

    // epilogue: per wave 128x64 block of C
#pragma unroll
    for (int mf = 0; mf < 8; ++mf) {
#pragma unroll
        for (int nf = 0; nf < 4; ++nf) {
            int col  = n0 + wn * 64 + nf * 16 + l16;
            float bv = bias[col];
#pragma unroll
            for (int r = 0; r < 4; ++r) {
                int row = m0 + wm * 128 + mf * 16 + quad * 4 + r;
                float v = acc[mf][nf][r] + bv;
                if (SCALE_OUT) v *= 0.08838834764831845f;  // 1/sqrt(128), Q only
                if (STORE_MODE == 0) {
                    ((float*)Cv)[(size_t)row * N + col] = v;
                } else {
                    ((__hip_bfloat16*)Cv)[(size_t)row * N + col] = __float2bfloat16(v);
                }
            }
        }
    }
}

// ---------------------------------------------------------------- GEMM (legacy 128x128)
// tight-workspace fallback (f32 inputs, sync cvt).
template <int A_ASYNC, int B_ASYNC, int STORE_MODE, int SCALE_OUT>
__global__ __launch_bounds__(256, 2) void gemm_k(const void* __restrict__ Av,
                                                 const void* __restrict__ Bv,
                                                 const float* __restrict__ bias,
                                                 void* __restrict__ Cv,
                                                 int M, int N, int K) {
    __shared__ __align__(16) __hip_bfloat16 sA[128 * 32];
    __shared__ __align__(16) __hip_bfloat16 sB[128 * 32];
    const int tid  = threadIdx.x;
    const int wave = tid >> 6, lane = tid & 63;
    const int quad = lane >> 4, l16 = lane & 15;
    const int m0 = blockIdx.x * 128, n0 = blockIdx.y * 128;
    const int wm = (wave >> 1) * 64, wn = (wave & 1) * 64;
    const int lrow   = lane >> 2;
    const int srcoff = (((lane & 3) ^ ((lane >> 3) & 3)) * 16);
    const int dstoff = (lane & 3) * 16;
    const int swzq   = (quad ^ ((l16 >> 1) & 3)) * 16;

    floatx4 acc[4][4];
#pragma unroll
    for (int i = 0; i < 4; i++)
#pragma unroll
        for (int j = 0; j < 4; j++) acc[i][j] = (floatx4)0.0f;

    for (int k0 = 0; k0 < K; k0 += 32) {
        short8 va[2], vb[2];
#pragma unroll
        for (int c = 0; c < 2; ++c) {
            int r = wave * 32 + c * 16 + lrow;
            if (!A_ASYNC) va[c] = cvt8((const float*)Av + (size_t)(m0 + r) * K + k0 + (lane & 3) * 8);
            if (!B_ASYNC) vb[c] = cvt8((const float*)Bv + (size_t)(n0 + r) * K + k0 + (lane & 3) * 8);
        }
        __syncthreads();
#pragma unroll
        for (int c = 0; c < 2; ++c) {
            int r = wave * 32 + c * 16 + lrow;
            if (A_ASYNC)
                async_copy16((const char*)((const __hip_bfloat16*)Av + (size_t)(m0 + r) * K + k0) + srcoff,
                             (char*)sA + r * 64 + dstoff);
            else
                *(short8*)((char*)sA + r * 64 + srcoff) = va[c];
            if (B_ASYNC)
                async_copy16((const char*)((const __hip_bfloat16*)Bv + (size_t)(n0 + r) * K + k0) + srcoff,
                             (char*)sB + r * 64 + dstoff);
            else
                *(short8*)((char*)sB + r * 64 + srcoff) = vb[c];
        }
        __syncthreads();

        short8 af[4], bf[4];
#pragma unroll
        for (int i = 0; i < 4; i++)
            af[i] = *(const short8*)((const char*)sA + (wm + i * 16 + l16) * 64 + swzq);
#pragma unroll
        for (int j = 0; j < 4; j++)
            bf[j] = *(const short8*)((const char*)sB + (wn + j * 16 + l16) * 64 + swzq);
#pragma unroll
        for (int i = 0; i < 4; i++)
#pragma unroll
            for (int j = 0; j < 4; j++)
                acc[i][j] = __builtin_amdgcn_mfma_f32_16x16x32_bf16(af[i], bf[j], acc[i][j], 0, 0, 0);
    }

#pragma unroll
    for (int i = 0; i < 4; i++) {
#pragma unroll
        for (int j = 0; j < 4; j++) {
            int col  = n0 + wn + j * 16 + l16;
            float bv = bias[col];
#pragma unroll
            for (int r = 0; r < 4; ++r) {
                int row = m0 + wm + i * 16 + quad * 4 + r;
                float v = acc[i][j][r] + bv;
                if (SCALE_OUT) v *= 0.08838834764831845f;
                if (STORE_MODE == 0) {
                    ((float*)Cv)[(size_t)row * N + col] = v;
                } else if (STORE_MODE == 1) {
                    ((__hip_bfloat16*)Cv)[(size_t)row * N + col] = __float2bfloat16(v);
                } else {
                    int s = row >> 2, b = row & 3, nh = col >> 7, d = col & 127;
                    ((__hip_bfloat16*)Cv)[((size_t)(b * 16 + nh) * 128 + d) * 2048 + s] =
                        __float2bfloat16(v);
                }
            }
        }
    }
}

// ---------------------------------------------------------------- RoPE (in-place)
// Q is pre-scaled by 1/sqrt(128) at the Q-gemm epilogue; rotation commutes with
// the scalar so rope is unchanged.
__global__ __launch_bounds__(256) void rope_kernel(__hip_bfloat16* __restrict__ Q,
                                                   __hip_bfloat16* __restrict__ K) {
    const int PER = 8192 * 16 * 32;
    int idx = (int)blockIdx.x * 256 + (int)threadIdx.x;
    __hip_bfloat16* base = (idx < PER) ? Q : K;
    int i  = (idx < PER) ? idx : idx - PER;
    int p  = i & 31;
    int nh = (i >> 5) & 15;
    int t  = i >> 9;
    int s  = t >> 2;
    float inv = __expf(-(float)(p & 15) * 0.5756462732485115f);  // ln(10000)/16
    float ang = (float)s * inv;
    float c = cosf(ang), sn = sinf(ang);
    size_t off = (size_t)t * 2048 + nh * 128 + 2 * p;
    float x0 = __bfloat162float(base[off]);
    float x1 = __bfloat162float(base[off + 1]);
    base[off]     = __float2bfloat16(x0 * c - x1 * sn);
    base[off + 1] = __float2bfloat16(x0 * sn + x1 * c);
}

// ---------------------------------------------------------------- flash attention
// r4-verified structure (swapped-operand in-register softmax + counted-vmcnt
// double buffer). r8: Q arrives pre-scaled (drops 32 muls/iter) + T13 defer-max
// (skip o_acc rescale when __all(mx <= m+8); P bounded by e^8, bf16-safe).
__global__ __launch_bounds__(256, 2) void attn_kernel(__hip_bfloat16* __restrict__ Qio,
                                                      const __hip_bfloat16* __restrict__ Km,
                                                      const __hip_bfloat16* __restrict__ Vt) {
    __shared__ __align__(16) char smem[65536];
    const int tid  = threadIdx.x;
    const int wave = tid >> 6, lane = tid & 63;
    const int quad = lane >> 4, l16 = lane & 15;
    const int bh = blockIdx.x, b = bh >> 4, nh = bh & 15;
    const int qtl = 15 - (int)blockIdx.y;
    const int q0  = qtl * 128;
    const int lrow    = lane >> 2;
    const int dstoff  = (lane & 3) * 16;
    const int srcoffV = (((lane & 3) ^ ((lane >> 3) & 3)) * 16);
    const int swzqV   = (quad ^ ((l16 >> 1) & 3)) * 16;

    auto stage = [&](int kt, int p) {
        char* sKb = smem + p * 32768;
        char* sVb = sKb + 16384;
#pragma unroll
        for (int c = 0; c < 4; ++c) {
            int krow = c * 16 + lrow;
            int swzK = ((krow >> 1) & 1) | (((krow >> 3) & 1) << 1);
            int srcK = ((lane & 3) ^ swzK) * 16;
            int t    = (kt * 64 + krow) * 4 + b;
            async_copy16((const char*)(Km + (size_t)t * 2048 + nh * 128 + wave * 32) + srcK,
                         sKb + wave * 4096 + krow * 64 + dstoff);
        }
        const int kc = wave >> 1, dh = (wave & 1) * 64;
#pragma unroll
        for (int c = 0; c < 4; ++c) {
            int d = dh + c * 16 + lrow;
            async_copy16((const char*)(Vt + ((size_t)bh * 128 + d) * 2048 + kt * 64 + kc * 32) + srcoffV,
                         sVb + kc * 8192 + d * 64 + dstoff);
        }
    };

    short8 qf[2][4];
#pragma unroll
    for (int mg = 0; mg < 2; ++mg)
#pragma unroll
        for (int kk = 0; kk < 4; ++kk) {
            int qrow = wave * 32 + mg * 16 + l16;
            int t    = (q0 + qrow) * 4 + b;
            qf[mg][kk] = *(const short8*)(Qio + (size_t)t * 2048 + nh * 128 + kk * 32 + quad * 8);
        }

    float m_i[2], l_i[2];
#pragma unroll
    for (int mg = 0; mg < 2; ++mg) { m_i[mg] = -1e30f; l_i[mg] = 0.f; }
    floatx4 o_acc[2][8];
#pragma unroll
    for (int mg = 0; mg < 2; ++mg)
#pragma unroll
        for (int n = 0; n < 8; ++n) o_acc[mg][n] = (floatx4)0.0f;

    const int nk = 2 * qtl + 2;

    stage(0, 0);
    __syncthreads();

    for (int kt = 0; kt < nk; ++kt) {
        const int cur = kt & 1;
        if (kt + 1 < nk) {
            stage(kt + 1, cur ^ 1);
            asm volatile("s_waitcnt vmcnt(8)" ::: "memory");
        } else {
            asm volatile("s_waitcnt vmcnt(0)" ::: "memory");
        }
        __builtin_amdgcn_s_barrier();
        __builtin_amdgcn_sched_barrier(0);

        const char* sKb = smem + cur * 32768;
        const char* sVb = sKb + 16384;

        floatx4 sacc[2][4];
#pragma unroll
        for (int mg = 0; mg < 2; ++mg)
#pragma unroll
            for (int n = 0; n < 4; ++n) sacc[mg][n] = (floatx4)0.0f;
#pragma unroll
        for (int nt = 0; nt < 4; ++nt) {
            int R    = (nt >> 1) * 32 + (l16 >> 2) * 8 + (nt & 1) * 4 + (l16 & 3);
            int swzK = ((R >> 1) & 1) | (((R >> 3) & 1) << 1);
            int off  = R * 64 + (quad ^ swzK) * 16;
#pragma unroll
            for (int kk = 0; kk < 4; ++kk) {
                short8 ak = *(const short8*)(sKb + kk * 4096 + off);
                sacc[0][nt] = __builtin_amdgcn_mfma_f32_16x16x32_bf16(ak, qf[0][kk], sacc[0][nt], 0, 0, 0);
                sacc[1][nt] = __builtin_amdgcn_mfma_f32_16x16x32_bf16(ak, qf[1][kk], sacc[1][nt], 0, 0, 0);
            }
        }

        short8 ap[2][2];
#pragma unroll
        for (int mg = 0; mg < 2; ++mg) {
            const int q     = q0 + wave * 32 + mg * 16 + l16;
            const bool dmask = (kt * 64 + 63) > (q0 + wave * 32 + mg * 16);
            float mx = -1e30f;
#pragma unroll
            for (int nt = 0; nt < 4; ++nt) {
                int kvb = kt * 64 + (nt >> 1) * 32 + quad * 8 + (nt & 1) * 4;
#pragma unroll
                for (int r = 0; r < 4; ++r) {
                    float v = sacc[mg][nt][r];   // Q pre-scaled: S*scale already
                    if (dmask && (kvb + r > q)) v = -1e30f;
                    sacc[mg][nt][r] = v;
                    mx = fmaxf(mx, v);
                }
            }
            mx = fmaxf(mx, __shfl_xor(mx, 16, 64));
            mx = fmaxf(mx, __shfl_xor(mx, 32, 64));
            // T13 defer-max: keep stale m when tile max within +8 (wave-uniform)
            const bool skip = __all(mx <= m_i[mg] + 8.0f) != 0;
            float alpha = 1.0f;
            if (!skip) {
                float mnew = fmaxf(m_i[mg], mx);
                alpha = __expf(m_i[mg] - mnew);
                m_i[mg] = mnew;
            }
            const float mref = m_i[mg];
            float rs = 0.f;
#pragma unroll
            for (int nt = 0; nt < 4; ++nt)
#pragma unroll
                for (int r = 0; r < 4; ++r) {
                    float e = __expf(sacc[mg][nt][r] - mref);
                    sacc[mg][nt][r] = e;
                    rs += e;
                }
            rs += __shfl_xor(rs, 16, 64);
            rs += __shfl_xor(rs, 32, 64);
            if (skip) {
                l_i[mg] += rs;
            } else {
                l_i[mg] = l_i[mg] * alpha + rs;
#pragma unroll
                for (int nt = 0; nt < 8; ++nt)
#pragma unroll
                    for (int r = 0; r < 4; ++r) o_acc[mg][nt][r] *= alpha;
            }
#pragma unroll
            for (int kc = 0; kc < 2; ++kc) {
                union { short s[8]; short8 v; } u;
                __hip_bfloat16* h = (__hip_bfloat16*)u.s;
                h[0] = __float2bfloat16(sacc[mg][2 * kc][0]);
                h[1] = __float2bfloat16(sacc[mg][2 * kc][1]);
                h[2] = __float2bfloat16(sacc[mg][2 * kc][2]);
                h[3] = __float2bfloat16(sacc[mg][2 * kc][3]);
                h[4] = __float2bfloat16(sacc[mg][2 * kc + 1][0]);
                h[5] = __float2bfloat16(sacc[mg][2 * kc + 1][1]);
                h[6] = __float2bfloat16(sacc[mg][2 * kc + 1][2]);
                h[7] = __float2bfloat16(sacc[mg][2 * kc + 1][3]);
                ap[mg][kc] = u.v;
            }
        }

#pragma unroll
        for (int kc = 0; kc < 2; ++kc)
#pragma unroll
            for (int nt = 0; nt < 8; ++nt) {
                short8 av = *(const short8*)(sVb + kc * 8192 + (nt * 16 + l16) * 64 + swzqV);
                o_acc[0][nt] = __builtin_amdgcn_mfma_f32_16x16x32_bf16(av, ap[0][kc], o_acc[0][nt], 0, 0, 0);
                o_acc[1][nt] = __builtin_amdgcn_mfma_f32_16x16x32_bf16(av, ap[1][kc], o_acc[1][nt], 0, 0, 0);
            }

        asm volatile("s_waitcnt lgkmcnt(0)" ::: "memory");
        __builtin_amdgcn_s_barrier();
        __builtin_amdgcn_sched_barrier(0);
    }

    char* sO = smem + wave * 4096;
#pragma unroll
    for (int mg = 0; mg < 2; ++mg) {
        float inv = 1.0f / l_i[mg];
#pragma unroll
        for (int nt = 0; nt < 8; ++nt) {
            union { short h[4]; uint2 v; } u;
            __hip_bfloat16* hh = (__hip_bfloat16*)u.h;
            hh[0] = __float2bfloat16(o_acc[mg][nt][0] * inv);
            hh[1] = __float2bfloat16(o_acc[mg][nt][1] * inv);
            hh[2] = __float2bfloat16(o_acc[mg][nt][2] * inv);
            hh[3] = __float2bfloat16(o_acc[mg][nt][3] * inv);
            int pc = (2 * nt + (quad >> 1)) ^ ((l16 >> 1) & 3);
            *(uint2*)(sO + l16 * 256 + pc * 16 + (quad & 1) * 8) = u.v;
        }
#pragma unroll
        for (int cc = 0; cc < 4; ++cc) {
            int qr  = lane >> 2;
            int c16 = (lane & 3) + cc * 4;
            int pc  = c16 ^ ((qr >> 1) & 3);
            short8 ov = *(const short8*)(sO + qr * 256 + pc * 16);
            int s = q0 + wave * 32 + mg * 16 + qr;
            *(short8*)(Qio + (size_t)(s * 4 + b) * 2048 + nh * 128 + c16 * 8) = ov;
        }
    }
}

// ---------------------------------------------------------------- launch
extern "C" void kernel_launch(void* const* d_in, const int* in_sizes, int n_in,
                              void* d_out, int out_size, void* d_ws, size_t ws_size,
                              hipStream_t stream) {
    const float* x  = (const float*)d_in[0];
    const float* wq = (const float*)d_in[1];
    const float* bq = (const float*)d_in[2];
    const float* wk = (const float*)d_in[3];
    const float* bk = (const float*)d_in[4];
    const float* wv = (const float*)d_in[5];
    const float* bv = (const float*)d_in[6];
    const float* wd = (const float*)d_in[7];
    const float* bd = (const float*)d_in[8];
    // d_in[9] = start_pos: unused (reference recomputes t=arange(seq))

    const size_t TH = (size_t)8192 * 2048;  // 16.7M elems

    if (ws_size >= (136ull << 20)) {
        // spacious: cvt x once; gemm256 consumes f32 weights directly (in-kernel
        // cvt during staging) -- the 4 weight-cvt kernels are gone.
        __hip_bfloat16* xb  = (__hip_bfloat16*)d_ws;
        __hip_bfloat16* Qb  = xb + TH;
        __hip_bfloat16* Kb  = Qb + TH;
        __hip_bfloat16* Vtb = Kb + TH;
        __hip_bfloat16* Vn  = (__hip_bfloat16*)d_out;  // scratch: V normal layout

        cvt_bf16<<<(int)(TH / 1024), 256, 0, stream>>>(x, xb, (int)TH);
        gemm256<1, 1><<<256, 512, 0, stream>>>(xb, wq, bq, Qb);  // Q pre-scaled
        gemm256<1, 0><<<256, 512, 0, stream>>>(xb, wk, bk, Kb);
        gemm256<1, 0><<<256, 512, 0, stream>>>(xb, wv, bv, Vn);
        vtrans<<<8192, 256, 0, stream>>>(Vn, Vtb);

        rope_kernel<<<32768, 256, 0, stream>>>(Qb, Kb);
        attn_kernel<<<dim3(64, 16), 256, 0, stream>>>(Qb, Kb, Vtb);

        gemm256<0, 0><<<256, 512, 0, stream>>>(Qb, wd, bd, d_out);
    } else {
        // tight (96 MiB total scratch): Q in ws; K,Vt inside d_out (legacy path)
        __hip_bfloat16* Qb = (__hip_bfloat16*)d_ws;
        __hip_bfloat16* Kb = (__hip_bfloat16*)d_out;
        __hip_bfloat16* Vt = (__hip_bfloat16*)d_out + TH;
        dim3 gg(64, 16);

        gemm_k<0, 0, 1, 1><<<gg, 256, 0, stream>>>(x, wq, bq, Qb, 8192, 2048, 2048);
        gemm_k<0, 0, 1, 0><<<gg, 256, 0, stream>>>(x, wk, bk, Kb, 8192, 2048, 2048);
        gemm_k<0, 0, 2, 0><<<gg, 256, 0, stream>>>(x, wv, bv, Vt, 8192, 2048, 2048);

        rope_kernel<<<32768, 256, 0, stream>>>(Qb, Kb);
        attn_kernel<<<dim3(64, 16), 256, 0, stream>>>(Qb, Kb, Vt);

        gemm_k<1, 0, 0, 0><<<gg, 256, 0, stream>>>(Qb, wd, bd, d_out, 8192, 2048, 2048);
    }
    (void)in_sizes; (void)n_in; (void)out_size; (void)ws_size;
}